// Round 3
// baseline (113.210 us; speedup 1.0000x reference)
//
#include <hip/hip_runtime.h>
#include <hip/hip_bf16.h>

// DistMult edge score: out[e] = sum_d node_emb[src[e]][d] * rel_emb[e][d] * node_emb[dst[e]][d]
// N_NODES=100000, N_EDGES=1000000, DIM=64 (fp32).
//
// R1 theory: rel_emb (256 MB, streamed once) thrashes the 256 MiB Infinity
// Cache, evicting the 25.6 MB node_emb table; the 2M random 256B gathers then
// miss L3 and hit HBM (~+500 MB) -> 110 us. Fix: non-temporal loads for the
// streaming operands (rel_emb, src, dst) and non-temporal store for out, so
// node_emb stays L3-resident and gathers are cache-served.
// R2 fix: __builtin_nontemporal_load requires a NATIVE vector type (clang
// ext_vector), not HIP's float4 class -> use float4n.

#define DIM 64
#define LANES_PER_EDGE 16

typedef __attribute__((ext_vector_type(4))) float float4n;

__global__ __launch_bounds__(256) void distmult_score_kernel(
    const float* __restrict__ node_emb,
    const float* __restrict__ rel_emb,
    const int* __restrict__ src,
    const int* __restrict__ dst,
    float* __restrict__ out,
    int n_edges)
{
    const int tid   = blockIdx.x * blockDim.x + threadIdx.x;
    const int lane  = tid & (LANES_PER_EDGE - 1);
    const int group = tid >> 4;
    const int n_groups = (gridDim.x * blockDim.x) >> 4;
    const int off = lane * 4;

    for (int e = group; e < n_edges; e += 2 * n_groups) {
        const int e2 = e + n_groups;
        const bool has2 = (e2 < n_edges);

        // Hoist all index loads (streaming -> non-temporal).
        const int s1 = __builtin_nontemporal_load(src + e);
        const int d1 = __builtin_nontemporal_load(dst + e);
        const int s2 = has2 ? __builtin_nontemporal_load(src + e2) : 0;
        const int d2 = has2 ? __builtin_nontemporal_load(dst + e2) : 0;

        // Edge 1 loads: rel is pure stream (nt); node gathers use normal
        // caching (we WANT them resident in L2/L3).
        const float4n r1 = __builtin_nontemporal_load(
            reinterpret_cast<const float4n*>(rel_emb + (size_t)e * DIM + off));
        const float4n h1 = *reinterpret_cast<const float4n*>(node_emb + (size_t)s1 * DIM + off);
        const float4n t1 = *reinterpret_cast<const float4n*>(node_emb + (size_t)d1 * DIM + off);

        float4n r2 = {0,0,0,0}, h2 = {0,0,0,0}, t2 = {0,0,0,0};
        if (has2) {
            r2 = __builtin_nontemporal_load(
                reinterpret_cast<const float4n*>(rel_emb + (size_t)e2 * DIM + off));
            h2 = *reinterpret_cast<const float4n*>(node_emb + (size_t)s2 * DIM + off);
            t2 = *reinterpret_cast<const float4n*>(node_emb + (size_t)d2 * DIM + off);
        }

        float p1 = h1.x * r1.x * t1.x
                 + h1.y * r1.y * t1.y
                 + h1.z * r1.z * t1.z
                 + h1.w * r1.w * t1.w;

        p1 += __shfl_xor(p1, 1, 64);
        p1 += __shfl_xor(p1, 2, 64);
        p1 += __shfl_xor(p1, 4, 64);
        p1 += __shfl_xor(p1, 8, 64);
        if (lane == 0) __builtin_nontemporal_store(p1, out + e);

        if (has2) {
            float p2 = h2.x * r2.x * t2.x
                     + h2.y * r2.y * t2.y
                     + h2.z * r2.z * t2.z
                     + h2.w * r2.w * t2.w;

            p2 += __shfl_xor(p2, 1, 64);
            p2 += __shfl_xor(p2, 2, 64);
            p2 += __shfl_xor(p2, 4, 64);
            p2 += __shfl_xor(p2, 8, 64);
            if (lane == 0) __builtin_nontemporal_store(p2, out + e2);
        }
    }
}

extern "C" void kernel_launch(void* const* d_in, const int* in_sizes, int n_in,
                              void* d_out, int out_size, void* d_ws, size_t ws_size,
                              hipStream_t stream) {
    const float* node_emb = (const float*)d_in[0];
    const float* rel_emb  = (const float*)d_in[1];
    const int*   src      = (const int*)d_in[2];
    const int*   dst      = (const int*)d_in[3];
    float*       out      = (float*)d_out;

    const int n_edges = in_sizes[2];  // src has one entry per edge

    const int block = 256;
    long long blocks_needed = ((long long)n_edges * LANES_PER_EDGE + block - 1) / block;
    int grid = (int)(blocks_needed < 2048 ? blocks_needed : 2048);

    distmult_score_kernel<<<grid, block, 0, stream>>>(node_emb, rel_emb, src, dst, out, n_edges);
}